// Round 3
// baseline (409.951 us; speedup 1.0000x reference)
//
#include <hip/hip_runtime.h>

// Fused SE(3) joint-update kernel.
//   revTwist = body_twist(T, revolute)
//   T        = T @ srodrigues(revolute,  q[n,0])
//   priTwist = body_twist(T, prismatic)
//   T        = T @ srodrigues(prismatic, q[n,1])
// Memory-bound: ~144 MB fetch + 224 MB write. Roofline ~57 us @ 6.5 TB/s.
// R3: fix — __builtin_nontemporal_* needs clang ext_vector types, not
// HIP_vector_type (float4 is a class). Use vf4/vf2 typedefs.

#define BLOCK 256

typedef float vf4 __attribute__((ext_vector_type(4)));
typedef float vf2 __attribute__((ext_vector_type(2)));

__device__ __forceinline__ void body_twist6(
    const vf4& r0, const vf4& r1, const vf4& r2,
    float wx, float wy, float wz, float vx, float vy, float vz,
    float t[6])
{
    const float px = r0.w, py = r1.w, pz = r2.w;
    // u = v - cross(p, w)
    const float ux = vx - (py * wz - pz * wy);
    const float uy = vy - (pz * wx - px * wz);
    const float uz = vz - (px * wy - py * wx);
    // wb = R^T w ; vb = R^T u
    t[0] = r0.x * wx + r1.x * wy + r2.x * wz;
    t[1] = r0.y * wx + r1.y * wy + r2.y * wz;
    t[2] = r0.z * wx + r1.z * wy + r2.z * wz;
    t[3] = r0.x * ux + r1.x * uy + r2.x * uz;
    t[4] = r0.y * ux + r1.y * uy + r2.y * uz;
    t[5] = r0.z * ux + r1.z * uy + r2.z * uz;
}

// T <- T @ srodrigues(xi, q); rows 0..2 updated in place, row 3 stays [0,0,0,1].
__device__ __forceinline__ void apply_srodrigues(
    vf4& r0, vf4& r1, vf4& r2,
    float th, bool rot,
    float wnx, float wny, float wnz,
    float vnx, float vny, float vnz,
    float vx, float vy, float vz,   // raw v for the !rot path
    float q)
{
    float R00, R01, R02, R10, R11, R12, R20, R21, R22, p0, p1, p2;
    if (rot) {
        const float phi = q * th;
        const float s  = __sinf(phi);   // native v_sin_f32: |phi| <~ 6, err ~1e-5 << 0.136 threshold
        const float cv = __cosf(phi);
        const float c  = 1.0f - cv;
        // R = I + s*skew(wn) + c*(wn wn^T - I)
        R00 = 1.0f + c * (wnx * wnx - 1.0f);
        R01 = -s * wnz + c * wnx * wny;
        R02 =  s * wny + c * wnx * wnz;
        R10 =  s * wnz + c * wny * wnx;
        R11 = 1.0f + c * (wny * wny - 1.0f);
        R12 = -s * wnx + c * wny * wnz;
        R20 = -s * wny + c * wnz * wnx;
        R21 =  s * wnx + c * wnz * wny;
        R22 = 1.0f + c * (wnz * wnz - 1.0f);
        // p = phi*vn + c*(wn x vn) + (phi - s)*(wn (wn.vn) - vn)
        const float d  = wnx * vnx + wny * vny + wnz * vnz;
        const float cx = wny * vnz - wnz * vny;
        const float cy = wnz * vnx - wnx * vnz;
        const float cz = wnx * vny - wny * vnx;
        const float ps = phi - s;
        p0 = phi * vnx + c * cx + ps * (wnx * d - vnx);
        p1 = phi * vny + c * cy + ps * (wny * d - vny);
        p2 = phi * vnz + c * cz + ps * (wnz * d - vnz);
    } else {
        R00 = 1.0f; R01 = 0.0f; R02 = 0.0f;
        R10 = 0.0f; R11 = 1.0f; R12 = 0.0f;
        R20 = 0.0f; R21 = 0.0f; R22 = 1.0f;
        p0 = q * vx; p1 = q * vy; p2 = q * vz;
    }
    vf4 n0, n1, n2;
    n0.x = r0.x * R00 + r0.y * R10 + r0.z * R20;
    n0.y = r0.x * R01 + r0.y * R11 + r0.z * R21;
    n0.z = r0.x * R02 + r0.y * R12 + r0.z * R22;
    n0.w = r0.x * p0  + r0.y * p1  + r0.z * p2 + r0.w;
    n1.x = r1.x * R00 + r1.y * R10 + r1.z * R20;
    n1.y = r1.x * R01 + r1.y * R11 + r1.z * R21;
    n1.z = r1.x * R02 + r1.y * R12 + r1.z * R22;
    n1.w = r1.x * p0  + r1.y * p1  + r1.z * p2 + r1.w;
    n2.x = r2.x * R00 + r2.y * R10 + r2.z * R20;
    n2.y = r2.x * R01 + r2.y * R11 + r2.z * R21;
    n2.z = r2.x * R02 + r2.y * R12 + r2.z * R22;
    n2.w = r2.x * p0  + r2.y * p1  + r2.z * p2 + r2.w;
    r0 = n0; r1 = n1; r2 = n2;
}

__global__ __launch_bounds__(BLOCK) void twist_66322884985439_kernel(
    const float* __restrict__ Tin,   // n*16, row-major 4x4
    const float* __restrict__ q2,    // n*2
    const float* __restrict__ rev,   // 6
    const float* __restrict__ pri,   // 6
    float* __restrict__ outRev,      // n*6
    float* __restrict__ outPri,      // n*6
    float* __restrict__ outT,        // n*16
    int n)
{
    __shared__ float sRev[BLOCK * 6];   // 6 KB — 2-way LDS bank aliasing (free)
    __shared__ float sPri[BLOCK * 6];   // 6 KB

    const int tid = threadIdx.x;
    const int blockStart = blockIdx.x * BLOCK;
    const int i = blockStart + tid;
    const bool active = i < n;
    const int li = active ? i : (n - 1);   // clamp: keep loads valid, skip stores

    // Uniform joint constants (scalar loads).
    const float rwx = rev[0], rwy = rev[1], rwz = rev[2];
    const float rvx = rev[3], rvy = rev[4], rvz = rev[5];
    const float pwx = pri[0], pwy = pri[1], pwz = pri[2];
    const float pvx = pri[3], pvy = pri[4], pvz = pri[5];

    const float rth  = sqrtf(rwx * rwx + rwy * rwy + rwz * rwz);
    const float rinv = 1.0f / fmaxf(rth, 1e-12f);
    const bool  rrot = rth > 1e-9f;
    const float rwnx = rwx * rinv, rwny = rwy * rinv, rwnz = rwz * rinv;
    const float rvnx = rvx * rinv, rvny = rvy * rinv, rvnz = rvz * rinv;

    const float pth  = sqrtf(pwx * pwx + pwy * pwy + pwz * pwz);
    const float pinv = 1.0f / fmaxf(pth, 1e-12f);
    const bool  prot = pth > 1e-9f;
    const float pwnx = pwx * pinv, pwny = pwy * pinv, pwnz = pwz * pinv;
    const float pvnx = pvx * pinv, pvny = pvy * pinv, pvnz = pvz * pinv;

    // Streaming loads (nontemporal: single-use data, don't reserve cache lines).
    const vf4* Tp = reinterpret_cast<const vf4*>(Tin + (size_t)li * 16);
    vf4 r0 = __builtin_nontemporal_load(Tp + 0);
    vf4 r1 = __builtin_nontemporal_load(Tp + 1);
    vf4 r2 = __builtin_nontemporal_load(Tp + 2);
    const vf2 q = __builtin_nontemporal_load(
        reinterpret_cast<const vf2*>(q2 + (size_t)li * 2));

    float tr[6], tp[6];
    body_twist6(r0, r1, r2, rwx, rwy, rwz, rvx, rvy, rvz, tr);
    apply_srodrigues(r0, r1, r2, rth, rrot, rwnx, rwny, rwnz, rvnx, rvny, rvnz,
                     rvx, rvy, rvz, q.x);
    body_twist6(r0, r1, r2, pwx, pwy, pwz, pvx, pvy, pvz, tp);
    apply_srodrigues(r0, r1, r2, pth, prot, pwnx, pwny, pwnz, pvnx, pvny, pvnz,
                     pvx, pvy, pvz, q.y);

    // Stage twists in LDS, flush fully coalesced.
    #pragma unroll
    for (int j = 0; j < 6; ++j) sRev[tid * 6 + j] = tr[j];
    #pragma unroll
    for (int j = 0; j < 6; ++j) sPri[tid * 6 + j] = tp[j];

    // T rows: 16B/lane stride-64B stores; each wave covers a contiguous 4 KB.
    if (active) {
        vf4* ot = reinterpret_cast<vf4*>(outT + (size_t)i * 16);
        __builtin_nontemporal_store(r0, ot + 0);
        __builtin_nontemporal_store(r1, ot + 1);
        __builtin_nontemporal_store(r2, ot + 2);
        const vf4 bottom = {0.0f, 0.0f, 0.0f, 1.0f};
        __builtin_nontemporal_store(bottom, ot + 3);
    }

    __syncthreads();

    const int cnt  = min(BLOCK, n - blockStart);  // tail block: n%256==128
    const int cnt6 = cnt * 6;
    const int nf4  = cnt6 >> 2;

    {
        const vf4* s4 = reinterpret_cast<const vf4*>(sRev);
        vf4* g4 = reinterpret_cast<vf4*>(outRev + (size_t)blockStart * 6);
        for (int idx = tid; idx < nf4; idx += BLOCK)
            __builtin_nontemporal_store(s4[idx], g4 + idx);
        for (int idx = (nf4 << 2) + tid; idx < cnt6; idx += BLOCK)  // dword tail (unused when cnt6%4==0)
            outRev[(size_t)blockStart * 6 + idx] = sRev[idx];
    }
    {
        const vf4* s4 = reinterpret_cast<const vf4*>(sPri);
        vf4* g4 = reinterpret_cast<vf4*>(outPri + (size_t)blockStart * 6);
        for (int idx = tid; idx < nf4; idx += BLOCK)
            __builtin_nontemporal_store(s4[idx], g4 + idx);
        for (int idx = (nf4 << 2) + tid; idx < cnt6; idx += BLOCK)
            outPri[(size_t)blockStart * 6 + idx] = sPri[idx];
    }
}

extern "C" void kernel_launch(void* const* d_in, const int* in_sizes, int n_in,
                              void* d_out, int out_size, void* d_ws, size_t ws_size,
                              hipStream_t stream) {
    const float* Tin = (const float*)d_in[0];   // (N,4,4) fp32
    const float* q2  = (const float*)d_in[1];   // (N,2)   fp32
    const float* rev = (const float*)d_in[2];   // (6,)    fp32
    const float* pri = (const float*)d_in[3];   // (6,)    fp32

    const int n = in_sizes[0] / 16;

    float* out = (float*)d_out;
    float* outRev = out;                        // n*6
    float* outPri = out + (size_t)n * 6;        // n*6
    float* outT   = out + (size_t)n * 12;       // n*16

    const int grid = (n + BLOCK - 1) / BLOCK;
    twist_66322884985439_kernel<<<grid, BLOCK, 0, stream>>>(
        Tin, q2, rev, pri, outRev, outPri, outT, n);
}